// Round 1
// baseline (1046.568 us; speedup 1.0000x reference)
//
#include <hip/hip_runtime.h>
#include <math.h>

// Battery cell physics (Daigle Li-ion model), direct serial transcription.
// One thread per cell: B=2048 cells, each runs T=1024 sequential Euler steps.
// Round 0: correctness baseline. Later rounds: decompose the affine scans
// (q-states, Vo/Vsn/Vsp) from the pointwise transcendental work.

__global__ __launch_bounds__(64) void battery_serial(
    const float* __restrict__ I,    // [B,T] current
    const float* __restrict__ X0,   // [B,8] initial state
    const float* __restrict__ Aps,  // [13]
    const float* __restrict__ Ans,  // [1]
    float* __restrict__ out,        // [B,T] voltage
    int Bn, int Tn)
{
    int b = blockIdx.x * blockDim.x + threadIdx.x;
    if (b >= Bn) return;

    // Model constants (computed in double, stored as f32)
    const float inv_qSMax = 1.0f / 1266.6666666666667f;  // qSMax = qmax*VolS/Volume
    const float Ro        = 0.117215f;
    const float invF      = 1.0f / 96487.0f;
    const float kn        = 2120.96f;
    const float kp        = 248898.0f;
    const float invVolB   = 1.0f / 1.8e-5f;
    const float invVolS   = 1.0f / 2.0e-6f;
    const float invTDiff  = 1.0f / 7.0e6f;
    const float invSn     = 1.0f / 0.000437545f;
    const float invSp     = 1.0f / 0.00030962f;
    const float inv_to    = 1.0f / 6.08671f;
    const float inv_tsn   = 1.0f / 1001.38f;
    const float inv_tsp   = 1.0f / 46.4311f;
    const float U0P = 4.03f, U0N = 0.01f;

    // Redlich-Kister coefficients (read from input; values are fixed by setup)
    float A[13], kA[13];
    #pragma unroll
    for (int k = 0; k < 13; ++k) A[k] = Aps[k];
    #pragma unroll
    for (int k = 0; k < 13; ++k) kA[k] = (float)k * A[k];
    const float An0 = Ans[0];

    float tb  = X0[b*8+0];
    float Vo  = X0[b*8+1];
    float Vsn = X0[b*8+2];
    float Vsp = X0[b*8+3];
    float qnB = X0[b*8+4];
    float qnS = X0[b*8+5];
    float qpB = X0[b*8+6];
    float qpS = X0[b*8+7];

    const float rtf  = 8.3144621f * tb * invF;  // R*tb/F
    const float rtfa = rtf * 2.0f;              // R*tb/(F*alpha), alpha=0.5

    const float* __restrict__ ip = I   + (size_t)b * Tn;
    float*       __restrict__ op = out + (size_t)b * Tn;

    for (int t = 0; t < Tn; ++t) {
        float it  = ip[t];
        float xpS = qpS * inv_qSMax;
        float xnS = qnS * inv_qSMax;

        float Jn0 = kn * sqrtf(xnS * (1.0f - xnS));   // (1-x)^.5 * x^.5
        float Jp0 = kp * sqrtf(xpS * (1.0f - xpS));

        float dBSn = (qnB * invVolB - qnS * invVolS) * invTDiff;
        float dBSp = (qpB * invVolB - qpS * invVolS) * invTDiff;

        float Jn = it * invSn;
        float Jp = it * invSp;
        float VoN = it * Ro;
        float VsnN = rtfa * asinhf(Jn / (2.0f * Jn0));
        float VspN = rtfa * asinhf(Jp / (2.0f * Jp0));

        // Ven: N=1 Redlich-Kister -> A0 * b / F  (k=0 second term is exactly 0)
        float bn = 2.0f * xnS - 1.0f;
        float vint_n = (xnS != 0.5f) ? (An0 * bn * invF) : 0.0f;
        float Ven = U0N + rtf * logf((1.0f - xnS) / xnS) + vint_n;

        // Vep: N=13 Redlich-Kister via two Horner polynomials in b
        //   sum_k A_k (b^{k+1} - 2x(1-x) k b^{k-1})
        //     = b * sum A_k b^k  -  2x(1-x) * sum_{k>=1} k A_k b^{k-1}
        float bp = 2.0f * xpS - 1.0f;
        float P1 = A[12];
        #pragma unroll
        for (int k = 11; k >= 0; --k) P1 = P1 * bp + A[k];
        float P2 = kA[12];
        #pragma unroll
        for (int k = 11; k >= 1; --k) P2 = P2 * bp + kA[k];
        float vint_p = (xpS != 0.5f)
                       ? ((bp * P1 - (2.0f * xpS * (1.0f - xpS)) * P2) * invF)
                       : 0.0f;
        float Vep = U0P + rtf * logf((1.0f - xpS) / xpS) + vint_p;

        // Output uses state BEFORE the update
        op[t] = Vep - Ven - Vo - Vsn - Vsp;

        // Euler updates (DT = 1)
        Vo  += (VoN  - Vo ) * inv_to;
        Vsn += (VsnN - Vsn) * inv_tsn;
        Vsp += (VspN - Vsp) * inv_tsp;
        qnB -= dBSn;
        qnS += (dBSn - it);
        qpB -= dBSp;
        qpS += (it + dBSp);
    }
}

extern "C" void kernel_launch(void* const* d_in, const int* in_sizes, int n_in,
                              void* d_out, int out_size, void* d_ws, size_t ws_size,
                              hipStream_t stream) {
    const float* I   = (const float*)d_in[0];
    const float* X0  = (const float*)d_in[1];
    const float* Aps = (const float*)d_in[2];
    const float* Ans = (const float*)d_in[3];
    float* out = (float*)d_out;

    int Bn = in_sizes[1] / 8;          // 2048
    int Tn = in_sizes[0] / Bn;         // 1024

    dim3 block(64);
    dim3 grid((Bn + 63) / 64);
    battery_serial<<<grid, block, 0, stream>>>(I, X0, Aps, Ans, out, Bn, Tn);
}

// Round 2
// 79.233 us; speedup vs baseline: 13.2088x; 13.2088x over previous
//
#include <hip/hip_runtime.h>
#include <math.h>

// Battery cell physics (Daigle Li-ion) — scan decomposition.
// Per cell the state recurrences are affine in i_t:
//   u = qB+qS          : u' = u -/+ i            (prefix sum)
//   w = qB/VolB-qS/VolS: w' = a_q w +/- i/VolS   (geometric scan, a_q const)
//   Vo               : Vo' = a_o Vo + (Ro/to) i  (geometric scan)
//   Vsn/Vsp          : geometric scans over VsnN/VspN (computed pointwise
//                      from xnS_t/xpS_t, which the q scans provide)
// Block per cell: 256 threads x 4 timesteps. Chunked Kogge-Stone with
// ratio-weighted combine (P_j += R^c * P_{j-c}) for the geometric scans.

constexpr int NTHR = 256;
constexpr int L = 4;

__global__ __launch_bounds__(NTHR) void battery_scan(
    const float* __restrict__ I, const float* __restrict__ X0,
    const float* __restrict__ Aps, const float* __restrict__ Ans,
    float* __restrict__ out, int Tn)
{
    const int cell = blockIdx.x;
    const int tid  = threadIdx.x;

    __shared__ float sh0[NTHR], sh1[NTHR], sh2[NTHR];

    // ---- model constants (double-folded at compile time) ----
    const float ivB    = (float)(1.0/1.8e-5);
    const float ivS    = (float)(1.0/2.0e-6);
    const float invSum = (float)(1.0/(1.0/1.8e-5 + 1.0/2.0e-6));
    const float aq     = (float)(1.0 - (1.0/1.8e-5 + 1.0/2.0e-6)/7.0e6);
    const float ao     = (float)(1.0 - 1.0/6.08671);
    const float asn    = (float)(1.0 - 1.0/1001.38);
    const float asp    = (float)(1.0 - 1.0/46.4311);
    const float inv_qS = (float)(1.0/1266.6666666666667);
    const float invF   = (float)(1.0/96487.0);
    const float kn     = 2120.96f, kp = 248898.0f;
    const float invSnH = (float)(0.5/0.000437545);   // 1/(2*Sn)
    const float invSpH = (float)(0.5/0.00030962);    // 1/(2*Sp)
    const float Ro_to  = (float)(0.117215/6.08671);
    const float inv_tsn= (float)(1.0/1001.38);
    const float inv_tsp= (float)(1.0/46.4311);
    const float U0P = 4.03f, U0N = 0.01f;

    const float aqp[4]  = {1.f, aq,  aq*aq,   aq*aq*aq};
    const float aop[4]  = {1.f, ao,  ao*ao,   ao*ao*ao};
    const float asnp[4] = {1.f, asn, asn*asn, asn*asn*asn};
    const float aspp[4] = {1.f, asp, asp*asp, asp*asp*asp};
    const float aq4 = aqp[3]*aq, ao4 = aop[3]*ao;
    const float asn4 = asnp[3]*asn, asp4 = aspp[3]*asp;

    // ---- per-cell initial state (uniform scalar loads) ----
    const float tb   = X0[cell*8+0];
    const float Vo0  = X0[cell*8+1];
    const float Vsn0 = X0[cell*8+2];
    const float Vsp0 = X0[cell*8+3];
    const float qnB0 = X0[cell*8+4];
    const float qnS0 = X0[cell*8+5];
    const float qpB0 = X0[cell*8+6];
    const float qpS0 = X0[cell*8+7];

    const float rtf  = 8.3144621f * tb * invF;
    const float rtfa = 2.f*rtf;
    const float u_n0 = qnB0 + qnS0;
    const float u_p0 = qpB0 + qpS0;
    const float w_n0 = qnB0*ivB - qnS0*ivS;
    const float w_p0 = qpB0*ivB - qpS0*ivS;
    const float An0  = Ans[0];

    // homogeneous decay bases a^(4*tid) (once per thread)
    const float t4 = (float)(tid*L);
    const float paq_base  = exp2f(t4 * __log2f(aq));
    const float pao_base  = exp2f(t4 * __log2f(ao));
    const float pasn_base = exp2f(t4 * __log2f(asn));
    const float pasp_base = exp2f(t4 * __log2f(asp));

    // ---- load this thread's 4 currents (coalesced float4) ----
    const float4 iv4 = *(const float4*)(I + (size_t)cell*Tn + tid*L);
    const float i4[4] = {iv4.x, iv4.y, iv4.z, iv4.w};

    // ---- phase A: exclusive scans of s (r=1), g (r=aq), o (r=ao) over i ----
    float es[4], eg[4], eo[4];
    {
        float as_=0.f, ag=0.f, aoc=0.f;
        #pragma unroll
        for (int k=0;k<L;++k){
            es[k]=as_; eg[k]=ag; eo[k]=aoc;
            float b = i4[k];
            as_ += b;
            ag  = aq*ag  + b;
            aoc = ao*aoc + b;
        }
        sh0[tid]=as_; sh1[tid]=ag; sh2[tid]=aoc;  // chunk totals
    }
    __syncthreads();
    {   // Kogge-Stone inclusive over chunk totals; weight R^shift for geometric
        float vs = sh0[tid], vg = sh1[tid], vo = sh2[tid];
        float Rg = aq4, Rr = ao4;
        for (int s=1; s<NTHR; s<<=1){
            float ps=0.f,pg=0.f,po=0.f;
            if (tid>=s){ ps=sh0[tid-s]; pg=sh1[tid-s]; po=sh2[tid-s]; }
            __syncthreads();
            vs += ps; vg += Rg*pg; vo += Rr*po;
            Rg*=Rg; Rr*=Rr;
            sh0[tid]=vs; sh1[tid]=vg; sh2[tid]=vo;
            __syncthreads();
        }
    }
    float cs=0.f, cg=0.f, co=0.f;
    if (tid>0){ cs=sh0[tid-1]; cg=sh1[tid-1]; co=sh2[tid-1]; }

    // ---- phase B: fully parallel transcendental pass ----
    float vpart[4], bsn[4], bsp[4];
    #pragma unroll
    for (int k=0;k<L;++k){
        float s_t = cs + es[k];
        float g_t = aqp[k]*cg + eg[k];
        float o_t = aop[k]*co + eo[k];
        float u_n = u_n0 - s_t, u_p = u_p0 + s_t;
        float paq = paq_base*aqp[k];
        float w_n = paq*w_n0 + ivS*g_t;
        float w_p = paq*w_p0 - ivS*g_t;
        float qnS = (u_n*ivB - w_n)*invSum;
        float qpS = (u_p*ivB - w_p)*invSum;
        float xnS = qnS*inv_qS, xpS = qpS*inv_qS;
        float Vo_t = (pao_base*aop[k])*Vo0 + Ro_to*o_t;
        float it = i4[k];
        float Jn0 = kn*sqrtf(xnS*(1.f-xnS));
        float Jp0 = kp*sqrtf(xpS*(1.f-xpS));
        float zn = __fdividef(it*invSnH, Jn0);
        float zp = __fdividef(it*invSpH, Jp0);
        // asinh(z) = ln(z + sqrt(z^2+1)), z > 0 here
        float VsnN = rtfa*__logf(zn + sqrtf(__builtin_fmaf(zn,zn,1.f)));
        float VspN = rtfa*__logf(zp + sqrtf(__builtin_fmaf(zp,zp,1.f)));
        float bn_ = 2.f*xnS - 1.f;
        float vint_n = (xnS != 0.5f) ? An0*bn_*invF : 0.f;
        float Ven = U0N + rtf*__logf(__fdividef(1.f-xnS, xnS)) + vint_n;
        float bp_ = 2.f*xpS - 1.f;
        float P1 = Aps[12];
        #pragma unroll
        for (int j=11;j>=0;--j) P1 = P1*bp_ + Aps[j];
        float P2 = 12.f*Aps[12];
        #pragma unroll
        for (int j=11;j>=1;--j) P2 = P2*bp_ + (float)j*Aps[j];
        float vint_p = (xpS != 0.5f)
                     ? (bp_*P1 - 2.f*xpS*(1.f-xpS)*P2)*invF : 0.f;
        float Vep = U0P + rtf*__logf(__fdividef(1.f-xpS, xpS)) + vint_p;
        vpart[k] = Vep - Ven - Vo_t;
        bsn[k] = VsnN * inv_tsn;
        bsp[k] = VspN * inv_tsp;
    }

    // ---- phase C: geometric scans for Vsn (asn) and Vsp (asp) ----
    float esn[4], esp[4];
    {
        float an=0.f, apv=0.f;
        #pragma unroll
        for (int k=0;k<L;++k){
            esn[k]=an; esp[k]=apv;
            an  = asn*an  + bsn[k];
            apv = asp*apv + bsp[k];
        }
        __syncthreads();            // protect LDS reuse
        sh0[tid]=an; sh1[tid]=apv;
    }
    __syncthreads();
    {
        float vn = sh0[tid], vp = sh1[tid];
        float Rn = asn4, Rp = asp4;
        for (int s=1; s<NTHR; s<<=1){
            float pn=0.f, pp=0.f;
            if (tid>=s){ pn=sh0[tid-s]; pp=sh1[tid-s]; }
            __syncthreads();
            vn += Rn*pn; vp += Rp*pp;
            Rn*=Rn; Rp*=Rp;
            sh0[tid]=vn; sh1[tid]=vp;
            __syncthreads();
        }
    }
    float csn=0.f, csp=0.f;
    if (tid>0){ csn=sh0[tid-1]; csp=sh1[tid-1]; }

    float res[4];
    #pragma unroll
    for (int k=0;k<L;++k){
        float Vsn_t = (pasn_base*asnp[k])*Vsn0 + (asnp[k]*csn + esn[k]);
        float Vsp_t = (pasp_base*aspp[k])*Vsp0 + (aspp[k]*csp + esp[k]);
        res[k] = vpart[k] - Vsn_t - Vsp_t;
    }
    *(float4*)(out + (size_t)cell*Tn + tid*L) = make_float4(res[0],res[1],res[2],res[3]);
}

extern "C" void kernel_launch(void* const* d_in, const int* in_sizes, int n_in,
                              void* d_out, int out_size, void* d_ws, size_t ws_size,
                              hipStream_t stream) {
    const float* I   = (const float*)d_in[0];
    const float* X0  = (const float*)d_in[1];
    const float* Aps = (const float*)d_in[2];
    const float* Ans = (const float*)d_in[3];
    float* out = (float*)d_out;

    int Bn = in_sizes[1] / 8;          // 2048
    int Tn = in_sizes[0] / Bn;         // 1024 == NTHR*L

    battery_scan<<<dim3(Bn), dim3(NTHR), 0, stream>>>(I, X0, Aps, Ans, out, Tn);
}

// Round 3
// 74.661 us; speedup vs baseline: 14.0176x; 1.0612x over previous
//
#include <hip/hip_runtime.h>
#include <math.h>

// Battery cell physics (Daigle Li-ion) — scan decomposition, v2.
// v2 changes vs v1:
//  - wave-level shuffle scans (no-barrier) + 4-entry cross-wave LDS combine:
//    barriers per block 32 -> 2
//  - trans diet: rsqrt for J0, merged electrode log; 12 -> 8 trans/elem
//  - dual Horner (P,P') using SGPR-resident Aps[] only
// Block = 256 threads (4 waves) per cell, L=4 timesteps/thread.

constexpr int NTHR = 256;
constexpr int L = 4;
constexpr int NW = NTHR / 64;

__global__ __launch_bounds__(NTHR, 6) void battery_scan2(
    const float* __restrict__ I, const float* __restrict__ X0,
    const float* __restrict__ Aps, const float* __restrict__ Ans,
    float* __restrict__ out, int Tn)
{
    const int cell = blockIdx.x;
    const int tid  = threadIdx.x;
    const int lane = tid & 63;
    const int wv   = tid >> 6;

    __shared__ float shA[3][NW];
    __shared__ float shC[2][NW];

    // ---- model constants (double-folded at compile time) ----
    const float ivB    = (float)(1.0/1.8e-5);
    const float ivS    = (float)(1.0/2.0e-6);
    const float invSum = (float)(1.0/(1.0/1.8e-5 + 1.0/2.0e-6));
    const float aq     = (float)(1.0 - (1.0/1.8e-5 + 1.0/2.0e-6)/7.0e6);
    const float ao     = (float)(1.0 - 1.0/6.08671);
    const float asn    = (float)(1.0 - 1.0/1001.38);
    const float asp    = (float)(1.0 - 1.0/46.4311);
    const float inv_qS = (float)(1.0/1266.6666666666667);
    const float invF   = (float)(1.0/96487.0);
    const float c_zn   = (float)(0.5/0.000437545/2120.96);   // 1/(2*Sn*kn)
    const float c_zp   = (float)(0.5/0.00030962/248898.0);   // 1/(2*Sp*kp)
    const float Ro_to  = (float)(0.117215/6.08671);
    const float inv_tsn= (float)(1.0/1001.38);
    const float inv_tsp= (float)(1.0/46.4311);
    const float U0PN   = 4.03f - 0.01f;                       // U0P - U0N

    const float aqp[4]  = {1.f, aq,  aq*aq,   aq*aq*aq};
    const float aop[4]  = {1.f, ao,  ao*ao,   ao*ao*ao};
    const float asnp[4] = {1.f, asn, asn*asn, asn*asn*asn};
    const float aspp[4] = {1.f, asp, asp*asp, asp*asp*asp};
    const float aq4 = aqp[3]*aq, ao4 = aop[3]*ao;
    const float asn4 = asnp[3]*asn, asp4 = aspp[3]*asp;

    // ---- per-cell initial state (uniform -> s_loads) ----
    const float tb   = X0[cell*8+0];
    const float Vo0  = X0[cell*8+1];
    const float Vsn0 = X0[cell*8+2];
    const float Vsp0 = X0[cell*8+3];
    const float qnB0 = X0[cell*8+4];
    const float qnS0 = X0[cell*8+5];
    const float qpB0 = X0[cell*8+6];
    const float qpS0 = X0[cell*8+7];
    const float An0  = Ans[0];

    const float rtf  = 8.3144621f * tb * invF;
    const float rtfa = 2.f*rtf;
    const float u_n0 = qnB0 + qnS0;
    const float u_p0 = qpB0 + qpS0;
    const float w_n0 = qnB0*ivB - qnS0*ivS;
    const float w_p0 = qpB0*ivB - qpS0*ivS;

    // per-lane ratio powers a^(4*lane) (one exp2 each, one-time)
    const float fl = (float)lane;
    const float plq  = exp2f(fl * __log2f(aq4));
    const float plo  = exp2f(fl * __log2f(ao4));
    const float pln  = exp2f(fl * __log2f(asn4));
    const float plp  = exp2f(fl * __log2f(asp4));

    // ---- load 4 currents (coalesced float4) ----
    const float4 iv4 = *(const float4*)(I + (size_t)cell*Tn + tid*L);
    const float i4[4] = {iv4.x, iv4.y, iv4.z, iv4.w};

    // wave-inclusive ratio scan over per-thread chunk totals.
    // After: ep = exclusive-for-thread prefix (within wave), Tw = wave total,
    // R64 = R4^64 (falls out of ratio squaring).
    auto wscan = [&](float tot, float R4, float& ep, float& Tw, float& R64) {
        float v = tot, r = R4;
        #pragma unroll
        for (int s = 1; s < 64; s <<= 1) {
            float p = __shfl_up(v, s);
            v = (lane >= s) ? fmaf(r, p, v) : v;
            r *= r;
        }
        float e = __shfl_up(v, 1);
        ep = (lane == 0) ? 0.f : e;
        Tw = __shfl(v, 63);
        R64 = r;
    };

    // ---- phase A: within-chunk exclusive scans + chunk totals ----
    float es[4], eg[4], eo[4];
    float ts = 0.f, tg = 0.f, to_ = 0.f;
    #pragma unroll
    for (int k = 0; k < L; ++k) {
        es[k] = ts; eg[k] = tg; eo[k] = to_;
        float b = i4[k];
        ts  += b;
        tg   = fmaf(aq, tg, b);
        to_  = fmaf(ao, to_, b);
    }
    float epS, TwS, RS, epG, TwG, RG, epO, TwO, RO;
    wscan(ts,  1.f, epS, TwS, RS);
    wscan(tg,  aq4, epG, TwG, RG);
    wscan(to_, ao4, epO, TwO, RO);
    if (lane == 0) { shA[0][wv] = TwS; shA[1][wv] = TwG; shA[2][wv] = TwO; }
    __syncthreads();
    float Cs = 0.f, Cg = 0.f, Co = 0.f;
    for (int w2 = 0; w2 < wv; ++w2) {
        Cs = Cs + shA[0][w2];
        Cg = fmaf(RG, Cg, 0.f) ; Cg = Cg; // placeholder removed below
        Co = Co;
        (void)0;
    }
    // proper Horner for geometric cross-wave prefixes (w<=3)
    Cs = 0.f; Cg = 0.f; Co = 0.f;
    for (int w2 = 0; w2 < wv; ++w2) {
        Cs = Cs + shA[0][w2];
        Cg = fmaf(Cg, RG, shA[1][w2]) - Cg*RG + Cg*RG; // = Cg*RG + shA
        Co = Co*RO + shA[2][w2];
    }
    // (rewrite cleanly)
    {
        Cs = 0.f; Cg = 0.f; Co = 0.f;
        #pragma unroll
        for (int w2 = 0; w2 < NW; ++w2) {
            if (w2 < wv) {
                Cs = Cs + shA[0][w2];
                Cg = Cg*RG + shA[1][w2];
                Co = Co*RO + shA[2][w2];
            }
        }
    }
    const float cs = epS + Cs;
    const float cg = fmaf(plq, Cg, epG);
    const float co = fmaf(plo, Co, epO);

    // homogeneous decay bases a^(4*tid) = pl * R64^wv
    float pwq = plq, pwo = plo;
    for (int w2 = 0; w2 < wv; ++w2) { pwq *= RG; pwo *= RO; }

    // ---- phase B: fully parallel transcendental pass ----
    float vpart[4], bsn[4], bsp[4];
    float tn_ = 0.f, tp_ = 0.f;   // chunk totals for phase C scans
    #pragma unroll
    for (int k = 0; k < L; ++k) {
        float s_t = cs + es[k];
        float g_t = fmaf(aqp[k], cg, eg[k]);
        float o_t = fmaf(aop[k], co, eo[k]);
        float u_n = u_n0 - s_t, u_p = u_p0 + s_t;
        float paq = pwq * aqp[k];
        float w_n = fmaf(paq, w_n0,  ivS*g_t);
        float w_p = fmaf(paq, w_p0, -ivS*g_t);
        float qnS = (u_n*ivB - w_n)*invSum;
        float qpS = (u_p*ivB - w_p)*invSum;
        float xnS = qnS*inv_qS, xpS = qpS*inv_qS;
        float Vo_t = fmaf(pwo*aop[k], Vo0, Ro_to*o_t);
        float it = i4[k];

        float pn = xnS*(1.f - xnS);
        float pp = xpS*(1.f - xpS);
        float zn = it * c_zn * rsqrtf(pn);
        float zp = it * c_zp * rsqrtf(pp);
        // asinh(z) = ln(z + sqrt(z^2+1))
        float VsnN = rtfa*__logf(zn + sqrtf(fmaf(zn, zn, 1.f)));
        float VspN = rtfa*__logf(zp + sqrtf(fmaf(zp, zp, 1.f)));

        // merged electrode logs: rtf*[log((1-xp)/xp) - log((1-xn)/xn)]
        float num = (1.f - xpS)*xnS;
        float den = xpS*(1.f - xnS);
        float lr  = __logf(__fdividef(num, den));

        // Redlich-Kister: dual Horner gives P (value) and D (derivative),
        // using only SGPR-resident Aps[j].
        float bp_ = 2.f*xpS - 1.f;
        float P = 0.f, D = 0.f;
        #pragma unroll
        for (int j = 12; j >= 0; --j) {
            D = fmaf(D, bp_, P);
            P = fmaf(P, bp_, Aps[j]);
        }
        float vint_p = (xpS != 0.5f)
                     ? (bp_*P - 2.f*xpS*(1.f - xpS)*D)*invF : 0.f;
        float bn_ = 2.f*xnS - 1.f;
        float vint_n = (xnS != 0.5f) ? An0*bn_*invF : 0.f;

        vpart[k] = U0PN + rtf*lr + vint_p - vint_n - Vo_t;
        float bn = VsnN * inv_tsn;
        float bpv = VspN * inv_tsp;
        bsn[k] = bn; bsp[k] = bpv;
        // accumulate chunk totals for phase C (in-order)
        tn_ = fmaf(asn, tn_, bn);
        tp_ = fmaf(asp, tp_, bpv);
    }

    // ---- phase C: geometric scans for Vsn (asn), Vsp (asp) ----
    float epN, TwN, RN, epP, TwP, RP;
    wscan(tn_, asn4, epN, TwN, RN);
    wscan(tp_, asp4, epP, TwP, RP);
    if (lane == 0) { shC[0][wv] = TwN; shC[1][wv] = TwP; }
    __syncthreads();
    float Cn = 0.f, Cp = 0.f;
    #pragma unroll
    for (int w2 = 0; w2 < NW; ++w2) {
        if (w2 < wv) {
            Cn = Cn*RN + shC[0][w2];
            Cp = Cp*RP + shC[1][w2];
        }
    }
    const float csn = fmaf(pln, Cn, epN);
    const float csp = fmaf(plp, Cp, epP);
    float pwn = pln, pwp = plp;
    for (int w2 = 0; w2 < wv; ++w2) { pwn *= RN; pwp *= RP; }

    float res[4];
    float an_ = 0.f, ap_ = 0.f;   // within-chunk exclusive re-run
    #pragma unroll
    for (int k = 0; k < L; ++k) {
        float Vsn_t = fmaf(pwn*asnp[k], Vsn0, fmaf(asnp[k], csn, an_));
        float Vsp_t = fmaf(pwp*aspp[k], Vsp0, fmaf(aspp[k], csp, ap_));
        res[k] = vpart[k] - Vsn_t - Vsp_t;
        an_ = fmaf(asn, an_, bsn[k]);
        ap_ = fmaf(asp, ap_, bsp[k]);
    }
    *(float4*)(out + (size_t)cell*Tn + tid*L) = make_float4(res[0],res[1],res[2],res[3]);
}

extern "C" void kernel_launch(void* const* d_in, const int* in_sizes, int n_in,
                              void* d_out, int out_size, void* d_ws, size_t ws_size,
                              hipStream_t stream) {
    const float* I   = (const float*)d_in[0];
    const float* X0  = (const float*)d_in[1];
    const float* Aps = (const float*)d_in[2];
    const float* Ans = (const float*)d_in[3];
    float* out = (float*)d_out;

    int Bn = in_sizes[1] / 8;          // 2048
    int Tn = in_sizes[0] / Bn;         // 1024 == NTHR*L

    battery_scan2<<<dim3(Bn), dim3(NTHR), 0, stream>>>(I, X0, Aps, Ans, out, Tn);
}

// Round 4
// 73.119 us; speedup vs baseline: 14.3132x; 1.0211x over previous
//
#include <hip/hip_runtime.h>
#include <math.h>

// Battery cell physics (Daigle Li-ion) — scan decomposition, v3.
// v3 vs v2:
//  - 128 threads/block (2 waves), L=8 elems/thread: half the waves, half the
//    scan overhead per element, trivial NW=2 cross-wave combine, fully
//    resident at 4 waves/EU.
//  - running-prefix form: seed S/G/O with the scan-produced chunk prefix and
//    advance the recurrence inline (no e-arrays, fewer FMAs, -24 VGPR).
//  - trans diet 8 -> 6/elem: asinh(zp) ~= zp(1 - zp^2/6) (zp <= 0.014 for
//    this model's parameter range, abs err < 1e-6), folded constants.

constexpr int NTHR = 128;
constexpr int L = 8;

__global__ __launch_bounds__(NTHR, 4) void battery_scan3(
    const float* __restrict__ I, const float* __restrict__ X0,
    const float* __restrict__ Aps, const float* __restrict__ Ans,
    float* __restrict__ out, int Tn)
{
    const int cell = blockIdx.x;
    const int tid  = threadIdx.x;
    const int lane = tid & 63;
    const int wv   = tid >> 6;          // 0 or 1

    __shared__ float shA[3][2];
    __shared__ float shC[2][2];

    // ---- model constants ----
    const float ivB    = (float)(1.0/1.8e-5);
    const float ivS    = (float)(1.0/2.0e-6);
    const float aq     = (float)(1.0 - (1.0/1.8e-5 + 1.0/2.0e-6)/7.0e6);
    const float ao     = (float)(1.0 - 1.0/6.08671);
    const float asn    = (float)(1.0 - 1.0/1001.38);
    const float asp    = (float)(1.0 - 1.0/46.4311);
    const float invSum = (float)(1.0/(1.0/1.8e-5 + 1.0/2.0e-6));
    const float cX     = (float)((1.0/(1.0/1.8e-5 + 1.0/2.0e-6)) / 1266.6666666666667); // invSum*inv_qS
    const float invF   = (float)(1.0/96487.0);
    const float c_zn   = (float)(0.5/0.000437545/2120.96);   // 1/(2*Sn*kn)
    const float c_zp   = (float)(0.5/0.00030962/248898.0);   // 1/(2*Sp*kp)
    const float Ro_to  = (float)(0.117215/6.08671);
    const float U0PN   = 4.03f - 0.01f;

    // ratio powers a^L (compile-time folded)
    float aqp = 1.f, aop = 1.f, asnp = 1.f, aspp = 1.f;
    #pragma unroll
    for (int k = 0; k < L; ++k) { aqp *= aq; aop *= ao; asnp *= asn; aspp *= asp; }
    const float aqL = aqp, aoL = aop, asnL = asnp, aspL = aspp;

    // ---- per-cell initial state ----
    const float tb   = X0[cell*8+0];
    const float Vo0  = X0[cell*8+1];
    const float Vsn0 = X0[cell*8+2];
    const float Vsp0 = X0[cell*8+3];
    const float qnB0 = X0[cell*8+4];
    const float qnS0 = X0[cell*8+5];
    const float qpB0 = X0[cell*8+6];
    const float qpS0 = X0[cell*8+7];
    const float An0F = Ans[0] * invF;

    const float rtf   = 8.3144621f * tb * invF;
    const float rtfa  = 2.f*rtf;
    const float bn_c  = rtfa * (float)(1.0/1001.38);  // rtfa*inv_tsn
    const float bp_c  = rtfa * (float)(1.0/46.4311);  // rtfa*inv_tsp
    const float u_n0  = qnB0 + qnS0;
    const float u_p0  = qpB0 + qpS0;
    const float w_n0  = qnB0*ivB - qnS0*ivS;
    const float w_p0  = qpB0*ivB - qpS0*ivS;

    // per-lane ratio powers (a^L)^lane
    const float fl = (float)lane;
    const float plq = exp2f(fl * __log2f(aqL));
    const float plo = exp2f(fl * __log2f(aoL));
    const float pln = exp2f(fl * __log2f(asnL));
    const float plp = exp2f(fl * __log2f(aspL));

    // ---- load this thread's 8 currents ----
    const float* ibase = I + (size_t)cell*Tn + tid*L;
    const float4 iva = *(const float4*)(ibase);
    const float4 ivb = *(const float4*)(ibase + 4);
    const float i8[8] = {iva.x, iva.y, iva.z, iva.w, ivb.x, ivb.y, ivb.z, ivb.w};

    // wave-level inclusive ratio scan over chunk totals.
    auto wscan = [&](float tot, float RL, float& ep, float& Tw, float& R64) {
        float v = tot, r = RL;
        #pragma unroll
        for (int s = 1; s < 64; s <<= 1) {
            float p = __shfl_up(v, s);
            v = (lane >= s) ? fmaf(r, p, v) : v;
            r *= r;
        }
        float e = __shfl_up(v, 1);
        ep = (lane == 0) ? 0.f : e;
        Tw = __shfl(v, 63);
        R64 = r;
    };

    // ---- phase A: chunk totals, wave scans, cross-wave combine ----
    float ts = 0.f, tg = 0.f, to_ = 0.f;
    #pragma unroll
    for (int k = 0; k < L; ++k) {
        float b = i8[k];
        ts += b; tg = fmaf(aq, tg, b); to_ = fmaf(ao, to_, b);
    }
    float epS, TwS, RS, epG, TwG, RG, epO, TwO, RO;
    wscan(ts,  1.f, epS, TwS, RS);
    wscan(tg,  aqL, epG, TwG, RG);
    wscan(to_, aoL, epO, TwO, RO);
    if (lane == 0) { shA[0][wv] = TwS; shA[1][wv] = TwG; shA[2][wv] = TwO; }
    __syncthreads();
    float cs = epS, cg = epG, co = epO;
    float pwq = plq, pwo = plo;
    if (wv) {
        cs += shA[0][0];
        cg = fmaf(plq, shA[1][0], cg);
        co = fmaf(plo, shA[2][0], co);
        pwq *= RG; pwo *= RO;
    }

    // ---- phase B: fully parallel pointwise pass ----
    float vpart[L], bsn[L], bsp[L];
    float S = cs, G = cg, O = co;          // running global exclusive prefixes
    float hwn = pwq*w_n0, hwp = pwq*w_p0;  // homogeneous decays
    float hvo = pwo*Vo0;
    float rn = 0.f, rp = 0.f;              // phase-C chunk totals
    #pragma unroll
    for (int k = 0; k < L; ++k) {
        float it  = i8[k];
        float u_n = u_n0 - S, u_p = u_p0 + S;
        float w_n = fmaf( ivS, G, hwn);
        float w_p = fmaf(-ivS, G, hwp);
        float xnS = (fmaf(u_n, ivB, -w_n)) * cX;
        float xpS = (fmaf(u_p, ivB, -w_p)) * cX;
        float Vo_t = fmaf(Ro_to, O, hvo);
        // advance recurrences
        S += it; G = fmaf(aq, G, it); O = fmaf(ao, O, it);
        hwn *= aq; hwp *= aq; hvo *= ao;

        float pn = fmaf(-xnS, xnS, xnS);       // xn(1-xn)
        float pp = fmaf(-xpS, xpS, xpS);
        float zn = it * c_zn * rsqrtf(pn);
        float zp = it * c_zp * rsqrtf(pp);
        // asinh(zn) exact; asinh(zp) ~= zp(1 - zp^2/6), zp <= 0.014
        float asn_n = __logf(zn + sqrtf(fmaf(zn, zn, 1.f)));
        float zp2  = zp*zp;
        float asn_p = zp * fmaf(-0.16666667f, zp2, 1.f);
        bsn[k] = bn_c * asn_n;
        bsp[k] = bp_c * asn_p;
        rn = fmaf(asn, rn, bsn[k]);
        rp = fmaf(asp, rp, bsp[k]);

        // merged electrode log: rtf*log( ((1-xp)*xn) / (xp*(1-xn)) )
        float omxn = 1.f - xnS, omxp = 1.f - xpS;
        float lr = __logf(__fdividef(omxp * xnS, xpS * omxn));

        // Redlich-Kister dual Horner (value P, derivative D)
        float b_ = fmaf(2.f, xpS, -1.f);
        float P = 0.f, D = 0.f;
        #pragma unroll
        for (int j = 12; j >= 0; --j) {
            D = fmaf(D, b_, P);
            P = fmaf(P, b_, Aps[j]);
        }
        float pp2 = pp + pp;                   // 2 xp (1-xp)
        float vint_p = (b_*P - pp2*D) * invF;
        vint_p = (xpS != 0.5f) ? vint_p : 0.f;
        float vint_n = An0F * fmaf(2.f, xnS, -1.f);

        vpart[k] = U0PN + fmaf(rtf, lr, vint_p - vint_n - Vo_t);
    }

    // ---- phase C: geometric scans for Vsn/Vsp ----
    float epN, TwN, RN, epP, TwP, RP;
    wscan(rn, asnL, epN, TwN, RN);
    wscan(rp, aspL, epP, TwP, RP);
    if (lane == 0) { shC[0][wv] = TwN; shC[1][wv] = TwP; }
    __syncthreads();
    float csn = epN, csp = epP;
    float pwn = pln, pwp = plp;
    if (wv) {
        csn = fmaf(pln, shC[0][0], csn);
        csp = fmaf(plp, shC[1][0], csp);
        pwn *= RN; pwp *= RP;
    }

    float N = csn, Pv = csp;
    float hn = pwn*Vsn0, hp = pwp*Vsp0;
    #pragma unroll
    for (int k = 0; k < L; ++k) {
        vpart[k] -= (hn + N) + (hp + Pv);
        N  = fmaf(asn, N,  bsn[k]);
        Pv = fmaf(asp, Pv, bsp[k]);
        hn *= asn; hp *= asp;
    }

    float* obase = out + (size_t)cell*Tn + tid*L;
    *(float4*)(obase)     = make_float4(vpart[0], vpart[1], vpart[2], vpart[3]);
    *(float4*)(obase + 4) = make_float4(vpart[4], vpart[5], vpart[6], vpart[7]);
}

extern "C" void kernel_launch(void* const* d_in, const int* in_sizes, int n_in,
                              void* d_out, int out_size, void* d_ws, size_t ws_size,
                              hipStream_t stream) {
    const float* I   = (const float*)d_in[0];
    const float* X0  = (const float*)d_in[1];
    const float* Aps = (const float*)d_in[2];
    const float* Ans = (const float*)d_in[3];
    float* out = (float*)d_out;

    int Bn = in_sizes[1] / 8;          // 2048
    int Tn = in_sizes[0] / Bn;         // 1024 == NTHR*L

    battery_scan3<<<dim3(Bn), dim3(NTHR), 0, stream>>>(I, X0, Aps, Ans, out, Tn);
}